// Round 12
// baseline (556.854 us; speedup 1.0000x reference)
//
#include <hip/hip_runtime.h>
#include <math.h>

typedef unsigned int u32;
typedef unsigned char u8;
typedef long i64;
typedef float f32x16 __attribute__((ext_vector_type(16)));

static constexpr int N = 4096;         // B*L
static constexpr int D = 1024;
static constexpr int V = 32000;
static constexpr int K = 8;
static constexpr int BM = 128;         // q rows per block
static constexpr int BV = 256;         // vocab rows per tile
static constexpr int NTILES = V / BV;  // 125 vocab tiles of 256
static constexpr int NG = 16;          // vocab groups (7 or 8 tiles each; cid < 2048)
static constexpr int NCAND = NG * K;   // 128 approx candidates per row
static constexpr int T24 = 24;         // rescored candidates per row
static constexpr int CPL = NCAND / 64; // 2 candidates per lane, exact
static constexpr int GRID = (N / BM) * NG;   // 512 = exactly 2 blocks/CU, zero tail
static constexpr u32 PSENT = 0x00800000u;    // packed(-3.4e38), unsigned-min sentinel

// d_out: [qnt 4MB | vnt 32.8MB | pad | cand @80MiB (2MB) | zero-tail @ZOFS .. N*V*4) [ids]
static constexpr size_t OUT_PROB_BYTES = (size_t)N * V * 4;            // 524,288,000
static constexpr size_t CAND_OFS = 83886080;                           // 80 MiB
static constexpr size_t ZOFS = CAND_OFS + (size_t)N * NCAND * 4;       // 85,983,232
static constexpr size_t NZ4 = (OUT_PROB_BYTES - ZOFS) / 16;            // 27,394,048 float4s

static_assert(N % BM == 0 && V % BV == 0, "tiling");
static_assert(ZOFS % 16 == 0, "align");
static_assert(NZ4 == (size_t)209 * GRID * 256, "zero quota exact");    // 209 <= 7*32 min stores

// float -> OCP e4m3 (RNE, clamp 448; subnormal below 2^-6). Filter-grade.
__device__ __forceinline__ u8 f2fp8(float f) {
  u32 u = __float_as_uint(f);
  u32 sign = (u >> 24) & 0x80u;
  u32 au = u & 0x7FFFFFFFu;
  if (au < 0x3D800000u) {                          // |f| < 2^-6: e4m3 subnormal (m*2^-9)
    int m = (int)(__uint_as_float(au) * 512.0f + 0.5f);
    return (u8)(sign | (u32)m);
  }
  au += 0x7FFFFu + ((au >> 20) & 1u);              // RNE to 3 mantissa bits
  if (au >= 0x43E00000u) return (u8)(sign | 0x7Eu);  // clamp to 448
  u32 e = (au >> 23) - 120u;                       // rebias 127 -> 7
  return (u8)(sign | (e << 3) | ((au >> 20) & 7u));
}
// monotone f32 -> sortable u32
__device__ __forceinline__ u32 flipbits(float v) {
  u32 u = __float_as_uint(v);
  return u ^ (((u32)((int)u >> 31)) | 0x80000000u);
}
// float upper bound of packed slot (11-bit cid field)
__device__ __forceinline__ float unpackval(u32 p) {
  u32 s = p | 2047u;
  u32 u = (s & 0x80000000u) ? (s ^ 0x80000000u) : ~s;
  return __uint_as_float(u);
}
// descending-sorted 8-slot insert, unsigned compare
__device__ __forceinline__ void insert8(u32 pv[K], u32 x) {
  if (x <= pv[K - 1]) return;
  bool g[K];
#pragma unroll
  for (int j = 0; j < K; ++j) g[j] = x > pv[j];
#pragma unroll
  for (int j = K - 1; j >= 1; --j)
    pv[j] = g[j - 1] ? pv[j - 1] : (g[j] ? x : pv[j]);
  if (g[0]) pv[0] = x;
}

// ---------------------------------------------------------------- zero (scratch region only)
__global__ void zero_kernel(float4* __restrict__ p, int n4) {
  int i = blockIdx.x * blockDim.x + threadIdx.x;
  int stride = gridDim.x * blockDim.x;
  float4 z = make_float4(0.f, 0.f, 0.f, 0.f);
  for (; i < n4; i += stride) p[i] = z;
}

// ---- fused: inverse L2 norm + normalized fp8 (x16) in K-MAJOR layout [c][row][8B]
// block = 32 rows; LDS transpose (padded u32 [32][257] -> conflict-free both phases)
__global__ __launch_bounds__(256)
void normcvtT_kernel(const float* __restrict__ x, float* __restrict__ inv,
                     u8* __restrict__ ot, int rows) {
  __shared__ u32 lt[32 * 257];
  const int tid = threadIdx.x, w = tid >> 6, l = tid & 63;
  const int rb = blockIdx.x * 32;
  // phase A: wave w norms+converts rows w*8..w*8+7, stashes fp8 rows in LDS
  for (int i = 0; i < 8; ++i) {
    int r = w * 8 + i;
    const float4* xr = reinterpret_cast<const float4*>(x + (size_t)(rb + r) * D);
    float4 v[4];
    float ss = 0.f;
#pragma unroll
    for (int j = 0; j < 4; ++j) {
      v[j] = xr[j * 64 + l];
      ss += v[j].x * v[j].x + v[j].y * v[j].y + v[j].z * v[j].z + v[j].w * v[j].w;
    }
#pragma unroll
    for (int off = 32; off > 0; off >>= 1) ss += __shfl_xor(ss, off, 64);
    float iv = 1.0f / fmaxf(sqrtf(ss), 1e-12f);
    if (l == 0) inv[rb + r] = iv;
    float sc = iv * 16.0f;                         // x16: e4m3 normal range
#pragma unroll
    for (int j = 0; j < 4; ++j) {
      u32 p = (u32)f2fp8(v[j].x * sc) | ((u32)f2fp8(v[j].y * sc) << 8) |
              ((u32)f2fp8(v[j].z * sc) << 16) | ((u32)f2fp8(v[j].w * sc) << 24);
      lt[r * 257 + j * 64 + l] = p;                // banks (l+const)%32 -> free
    }
  }
  __syncthreads();
  // phase B: write chunks; lane group (r=tid&31, cg=tid>>5) -> coalesced 8B/row
  const int r = tid & 31, cg = tid >> 5;
#pragma unroll
  for (int i = 0; i < 16; ++i) {
    int c = cg + 8 * i;                            // 0..127
    u32 lo = lt[r * 257 + c * 2];
    u32 hi = lt[r * 257 + c * 2 + 1];
    *reinterpret_cast<unsigned long long*>(ot + ((size_t)c * rows + rb + r) * 8) =
        (unsigned long long)lo | ((unsigned long long)hi << 32);
  }
}

// ------- fp8 MFMA sims, NO-LDS register GEMM (K-major operands, direct coalesced
// loads, zero barriers in the k-loop). SWAPPED operands (A=vocab, B=query) keep the
// in-register top-8 scan. 2-deep ping-pong prefetch is race-free without barriers.
// Frag map (validated r10/r11): lane&31 -> row, lane>>5 -> 8-elem k-half.
__global__ __launch_bounds__(256, 2)
void simtopk_kernel(const u8* __restrict__ qnt, const u8* __restrict__ vnt,
                    u32* __restrict__ cand, float4* __restrict__ zout) {
  __shared__ u32 marr[BM * 4 * K];                 // 16 KB, merge only

  const int tid = threadIdx.x;
  const int bid = blockIdx.x;
  // XCD-aware: XCD x (=bid&7) owns groups 2x,2x+1; rowblock fast-varying.
  const int u_ = bid >> 3;                         // 0..63
  const int rb = u_ & 31;                          // rowblock
  const int grp = (bid & 7) * 2 + (u_ >> 5);       // vocab group 0..15
  const int t0 = (grp * NTILES) >> 4;              // first vocab tile
  const int t1 = ((grp + 1) * NTILES) >> 4;        // past-last (t1-t0 = 7 or 8)
  const int rbase = rb * BM;
  const int wid = tid >> 6, l = tid & 63;
  const int wv = wid >> 1, wq = wid & 1;           // wave: vocab half x query half
  const int h = l >> 5, lid = l & 31;

  const float4 zf4 = make_float4(0.f, 0.f, 0.f, 0.f);

  u32 pv[2][K];                                    // packed top-8 per owned q-row
#pragma unroll
  for (int n = 0; n < 2; ++n)
#pragma unroll
    for (int j = 0; j < K; ++j) pv[n][j] = PSENT;
  float tminf[2] = {-3.0e38f, -3.0e38f};

  f32x16 acc[4][2];
#pragma unroll
  for (int m = 0; m < 4; ++m)
#pragma unroll
    for (int n = 0; n < 2; ++n)
#pragma unroll
      for (int r = 0; r < 16; ++r) acc[m][n][r] = 0.f;

  auto LOADF = [&](int ti, int t, i64* vf, i64* qf) {  // 6 coalesced dwordx2 loads
    const u8* vp = vnt + ((size_t)(2 * t + h) * V + (size_t)ti * BV + wv * 128 + lid) * 8;
    const u8* qp = qnt + ((size_t)(2 * t + h) * N + rbase + wq * 64 + lid) * 8;
#pragma unroll
    for (int m = 0; m < 4; ++m) vf[m] = *reinterpret_cast<const i64*>(vp + m * 256);
#pragma unroll
    for (int n = 0; n < 2; ++n) qf[n] = *reinterpret_cast<const i64*>(qp + n * 256);
  };

  auto MFMA8 = [&](i64* vf, i64* qf) {
    __builtin_amdgcn_s_setprio(1);
#pragma unroll
    for (int m = 0; m < 4; ++m)
#pragma unroll
      for (int n = 0; n < 2; ++n)
        acc[m][n] = __builtin_amdgcn_mfma_f32_32x32x16_fp8_fp8(vf[m], qf[n], acc[m][n], 0, 0, 0);
    __builtin_amdgcn_s_setprio(0);
  };

  auto SCAN = [&](int tcnt) {                      // in-register top-8 scan + acc reset
    const int cb = tcnt * BV;
#pragma unroll
    for (int n = 0; n < 2; ++n) {
#pragma unroll
      for (int m = 0; m < 4; ++m) {
        f32x16 a = acc[m][n];
        float x01 = fmaxf(a[0], a[1]),   x23 = fmaxf(a[2], a[3]);
        float x45 = fmaxf(a[4], a[5]),   x67 = fmaxf(a[6], a[7]);
        float x89 = fmaxf(a[8], a[9]),   xab = fmaxf(a[10], a[11]);
        float xcd = fmaxf(a[12], a[13]), xef = fmaxf(a[14], a[15]);
        float mx = fmaxf(fmaxf(fmaxf(x01, x23), fmaxf(x45, x67)),
                         fmaxf(fmaxf(x89, xab), fmaxf(xcd, xef)));
        if (mx > tminf[n]) {
          const int cidb = cb + wv * 128 + m * 32 + 4 * h;
#pragma unroll
          for (int r = 0; r < 16; ++r) {
            float v = a[r];
            if (v > tminf[n]) {
              int cid = cidb + (r & 3) + 8 * (r >> 2);
              u32 p = (flipbits(v) & 0xFFFFF800u) | (u32)(2047 - cid);
              insert8(pv[n], p);
            }
          }
          tminf[n] = unpackval(pv[n][K - 1]);
        }
      }
    }
#pragma unroll
    for (int m = 0; m < 4; ++m)
#pragma unroll
      for (int n = 0; n < 2; ++n)
#pragma unroll
        for (int r = 0; r < 16; ++r) acc[m][n][r] = 0.f;
  };

  i64 va[4], qa[2], vb[4], qb[2];
  for (int ti = t0; ti < t1; ++ti) {
    const int tcnt = ti - t0;
    LOADF(ti, 0, va, qa);
    for (int t = 0; t < 64; t += 2) {              // D/16 = 64 t-steps, ping-pong
      LOADF(ti, t + 1, vb, qb);
      {                                            // fused zero-fill (no sync needed)
        int s = tcnt * 32 + (t >> 1);
        if (s < 209) zout[(size_t)s * (GRID * 256) + bid * 256 + tid] = zf4;
      }
      MFMA8(va, qa);
      if (t + 2 < 64) LOADF(ti, t + 2, va, qa);
      MFMA8(vb, qb);
    }
    SCAN(tcnt);
  }

  // ---- merge 4 contributors (wv x h) per q-row -> per-group top-8
  __syncthreads();
#pragma unroll
  for (int n = 0; n < 2; ++n)
#pragma unroll
    for (int j = 0; j < K; ++j)
      marr[((wq * 64 + n * 32 + lid) * 4 + (wv * 2 + h)) * K + j] = pv[n][j];
  __syncthreads();
  if (tid < BM) {
    u32 fv[K];
#pragma unroll
    for (int j = 0; j < K; ++j) fv[j] = PSENT;
#pragma unroll
    for (int c4 = 0; c4 < 4; ++c4)
#pragma unroll
      for (int j = 0; j < K; ++j) insert8(fv, marr[(tid * 4 + c4) * K + j]);
#pragma unroll
    for (int j = 0; j < K; ++j)
      cand[(size_t)(rbase + tid) * NCAND + grp * K + j] = fv[j];
  }
}

// ------- approx top-24 merge + exact fp32 rescore + top-8 + softmax (1 wave/row)
__global__ __launch_bounds__(256)
void rescore_kernel(const u32* __restrict__ cand,
                    const float* __restrict__ emb, const float* __restrict__ vocab,
                    const float* __restrict__ invq, const float* __restrict__ invv,
                    float* __restrict__ res_p, int* __restrict__ res_i) {
  const int tid = threadIdx.x, wid = tid >> 6, l = tid & 63;
  const int row = blockIdx.x * 4 + wid;

  float4 q[4];                                     // emb row: lane l holds float4s t*64+l
#pragma unroll
  for (int t = 0; t < 4; ++t)
    q[t] = *(reinterpret_cast<const float4*>(emb + (size_t)row * D) + t * 64 + l);
  float iqr = invq[row];

  u32 pl[CPL]; int li[CPL];                        // packed candidates + global ids
#pragma unroll
  for (int t = 0; t < CPL; ++t) {
    int e = l * CPL + t;
    u32 p = cand[(size_t)row * NCAND + e];
    int grp = e >> 3;
    int tile0 = (grp * NTILES) >> 4;               // group's first vocab tile
    pl[t] = p;
    li[t] = tile0 * BV + 2047 - (int)(p & 2047u);
  }

  int cidx[T24];                                   // approx top-24 by iterative extraction
#pragma unroll
  for (int jr = 0; jr < T24; ++jr) {
    u32 bp = pl[0]; int bi = li[0];
#pragma unroll
    for (int t = 1; t < CPL; ++t)
      if (pl[t] > bp || (pl[t] == bp && li[t] < bi)) { bp = pl[t]; bi = li[t]; }
#pragma unroll
    for (int off = 32; off > 0; off >>= 1) {
      u32 op = (u32)__shfl_xor((int)bp, off, 64); int oi = __shfl_xor(bi, off, 64);
      if (op > bp || (op == bp && oi < bi)) { bp = op; bi = oi; }
    }
    cidx[jr] = bi;
#pragma unroll
    for (int t = 0; t < CPL; ++t) if (li[t] == bi) pl[t] = 0u;
  }

  float sv[T24];                                   // exact fp32 cosine for each candidate
#pragma unroll
  for (int jr = 0; jr < T24; ++jr) {
    int ix = cidx[jr];
    const float4* vr = reinterpret_cast<const float4*>(vocab + (size_t)ix * D);
    float s = 0.f;
#pragma unroll
    for (int t = 0; t < 4; ++t) {
      float4 vv = vr[t * 64 + l];
      s += q[t].x * vv.x + q[t].y * vv.y + q[t].z * vv.z + q[t].w * vv.w;
    }
#pragma unroll
    for (int off = 32; off > 0; off >>= 1) s += __shfl_xor(s, off, 64);
    sv[jr] = s * iqr * invv[ix];
  }

  float pvv[K]; int pii[K];                        // exact top-8, idx-asc on ties
#pragma unroll
  for (int r8 = 0; r8 < K; ++r8) {
    float bv = sv[0]; int bi = cidx[0];
#pragma unroll
    for (int jr = 1; jr < T24; ++jr)
      if (sv[jr] > bv || (sv[jr] == bv && cidx[jr] < bi)) { bv = sv[jr]; bi = cidx[jr]; }
    pvv[r8] = bv; pii[r8] = bi;
#pragma unroll
    for (int jr = 0; jr < T24; ++jr) if (cidx[jr] == bi) sv[jr] = -3.0e38f;
  }

  float m = pvv[0], sum = 0.f, e8[K];
#pragma unroll
  for (int j = 0; j < K; ++j) { e8[j] = expf(pvv[j] - m); sum += e8[j]; }
  float isum = 1.f / sum;
  if (l == 0) {
#pragma unroll
    for (int j = 0; j < K; ++j) {
      res_p[row * K + j] = e8[j] * isum;
      res_i[row * K + j] = pii[j];
    }
  }
}

// --------------------------------------------- final scatter into zeroed probs
__global__ void scatter_kernel(const float* __restrict__ res_p, const int* __restrict__ res_i,
                               float* __restrict__ out) {
  int row = blockIdx.x * blockDim.x + threadIdx.x;
#pragma unroll
  for (int j = 0; j < K; ++j) out[(size_t)row * V + res_i[row * K + j]] = res_p[row * K + j];
  out[(size_t)N * V + row] = (float)res_i[row * K];  // token id = exact argmax
}

extern "C" void kernel_launch(void* const* d_in, const int* in_sizes, int n_in,
                              void* d_out, int out_size, void* d_ws, size_t ws_size,
                              hipStream_t stream) {
  const float* emb   = (const float*)d_in[0];
  const float* vocab = (const float*)d_in[1];
  float* out = (float*)d_out;

  // scratch carved out of d_out (probs region; re-zeroed before scatter)
  u8* qnt = (u8*)d_out;                                    // 4 MB fp8 Q, K-major [c][row]
  u8* vnt = qnt + (size_t)128 * N * 8;                     // 32.8 MB fp8 V, K-major
  u32* cand = (u32*)((char*)d_out + CAND_OFS);             // 2 MB
  float4* ztail = (float4*)((char*)d_out + ZOFS);          // zero-fill target in simtopk

  float* wsf   = (float*)d_ws;
  float* invq  = wsf;                                      // N
  float* invv  = wsf + N;                                  // V
  float* res_p = wsf + N + V;                              // N*K
  int*   res_i = (int*)(wsf + N + V + N * K);              // N*K

  normcvtT_kernel<<<N / 32, 256, 0, stream>>>(emb, invq, qnt, N);
  normcvtT_kernel<<<V / 32, 256, 0, stream>>>(vocab, invv, vnt, V);
  simtopk_kernel<<<GRID, 256, 0, stream>>>(qnt, vnt, cand, ztail);
  rescore_kernel<<<N / 4, 256, 0, stream>>>(cand, emb, vocab, invq, invv, res_p, res_i);
  zero_kernel<<<2048, 256, 0, stream>>>((float4*)d_out, (int)(ZOFS / 16));  // scratch region
  scatter_kernel<<<N / 256, 256, 0, stream>>>(res_p, res_i, out);
}